// Round 4
// baseline (1880.491 us; speedup 1.0000x reference)
//
#include <hip/hip_runtime.h>

#define TT 32

// ---------- bf16 helpers (OCP bfloat16, RNE) ----------
__device__ __forceinline__ float bf16_bits_to_f32(unsigned short u) {
    unsigned v = ((unsigned)u) << 16; float f; __builtin_memcpy(&f, &v, 4); return f;
}
__device__ __forceinline__ unsigned short f32_to_bf16_rne(float f) {
    unsigned u; __builtin_memcpy(&u, &f, 4);
    u += 0x7FFFu + ((u >> 16) & 1u);            // round-to-nearest-even
    return (unsigned short)(u >> 16);
}
__device__ __forceinline__ float round_bf16_f32(float f) {  // f32 -> bf16 -> f32 value
    return bf16_bits_to_f32(f32_to_bf16_rne(f));
}
// Correctly-rounded f64 -> bf16 (single rounding): round-to-odd to f32, then RNE.
__device__ __forceinline__ float f64_to_bf16_f32(double d) {
    float fz = __double2float_rz(d);
    if ((double)fz != d) {
        unsigned u; __builtin_memcpy(&u, &fz, 4); u |= 1u; __builtin_memcpy(&fz, &u, 4);
    }
    return round_bf16_f32(fz);
}

// ---------- dtype detect + init ----------
// fp32 spike words are exactly {0, 0x3F800000}. bf16-pair words hit other
// patterns with P=0.3/word -> P(misclassify bf16 as f32) = 0.7^64 ~ 1e-10.
__global__ void detect_and_init(const unsigned* __restrict__ spk,
                                int* __restrict__ flag, float* __restrict__ sums)
{
    unsigned w = spk[threadIdx.x];
    bool ok = (w == 0u) || (w == 0x3F800000u);
    unsigned long long vote = __ballot(ok);
    if (threadIdx.x == 0) {
        flag[0] = (vote == 0xFFFFFFFFFFFFFFFFull) ? 0 : 1;  // 0=f32, 1=bf16
        sums[0] = 0.f; sums[1] = 0.f; sums[2] = 0.f;
    }
}

// ---------- fused ConvT(stride2,k3,pad1, w*2) + CUBA scan ----------
// One thread = one output site (n,co,oh,ow). z[32] accumulated exactly in f64.
// bf16 mode: z and each scan-add are RNE-rounded to bf16, replicating a
// bf16-dtype reference (XLA / ml_dtypes semantics: f32-compute, bf16-demote;
// *0.5, *(1-s), weight*2 are exact in bf16 so only the adds round).
// Intermediate spikes are BIT-PACKED: one u32 mask (T=32) per site (<3MB ws).
template<int CIN, int COUT, bool FIRST, bool LAST>
__global__ __launch_bounds__(256)
void cuba_layer(const void* __restrict__ ginv, const unsigned* __restrict__ inMask,
                const void* __restrict__ wptr, void* __restrict__ goutv,
                unsigned* __restrict__ outMask, int N, int Hi, int Wi,
                float* __restrict__ sumOut, const int* __restrict__ flag)
{
    const bool isbf = (flag[0] != 0);
    const int Ho = 2 * Hi - 1, Wo = 2 * Wi - 1;
    const int total = N * COUT * Ho * Wo;
    const int gid = blockIdx.x * 256 + threadIdx.x;
    float cnt = 0.0f;

    if (gid < total) {
        int ow = gid % Wo;
        int t1 = gid / Wo;
        int oh = t1 % Ho;
        int t2 = t1 / Ho;
        int co = t2 % COUT;
        int n  = t2 / COUT;

        // Parity-decomposed transposed-conv taps (all in-bounds, Ho=2Hi-1, pad=1):
        // even o: x[o/2]*w[1];  odd o: x[(o-1)/2]*w[2] + x[(o+1)/2]*w[0].
        int ihs[2], khs[2], iws[2], kws[2];
        int nV, nH;
        if (oh & 1) { nV = 2; ihs[0] = (oh - 1) >> 1; khs[0] = 2;
                              ihs[1] = (oh + 1) >> 1; khs[1] = 0; }
        else        { nV = 1; ihs[0] = oh >> 1;       khs[0] = 1; }
        if (ow & 1) { nH = 2; iws[0] = (ow - 1) >> 1; kws[0] = 2;
                              iws[1] = (ow + 1) >> 1; kws[1] = 0; }
        else        { nH = 1; iws[0] = ow >> 1;       kws[0] = 1; }

        const int nT = nV * nH;
        int site[4], wof[4];                 // site index (no T), weight tap offset
        {
            int c = 0;
            for (int v = 0; v < nV; ++v)
                for (int h = 0; h < nH; ++h) {
                    site[c] = ihs[v] * Wi + iws[h];
                    wof[c]  = khs[v] * 3 + kws[h];
                    ++c;
                }
        }

        double acc[TT];
        #pragma unroll
        for (int t = 0; t < TT; ++t) acc[t] = 0.0;

        const int planeSites = Hi * Wi;

        for (int cin = 0; cin < CIN; ++cin) {
            const int sBase = (n * CIN + cin) * planeSites;
            const int wbase = cin * COUT * 9 + co * 9;
            for (int tp = 0; tp < nT; ++tp) {
                // weight_scale=2 folded: *2 is exact in bf16 and f32.
                const float wraw = isbf
                    ? bf16_bits_to_f32(((const unsigned short*)wptr)[wbase + wof[tp]])
                    : ((const float*)wptr)[wbase + wof[tp]];
                const double wv = 2.0 * (double)wraw;
                const int s = sBase + site[tp];

                if (FIRST) {
                    if (isbf) {
                        const uint4* p = (const uint4*)((const unsigned short*)ginv + (size_t)s * TT);
                        #pragma unroll
                        for (int q = 0; q < 4; ++q) {
                            uint4 a = p[q];
                            unsigned wd[4] = {a.x, a.y, a.z, a.w};
                            #pragma unroll
                            for (int m = 0; m < 4; ++m) {
                                const int t = q * 8 + m * 2;
                                acc[t]   += (wd[m] & 0xFFFFu) ? wv : 0.0;
                                acc[t+1] += (wd[m] >> 16)     ? wv : 0.0;
                            }
                        }
                    } else {
                        const float4* p = (const float4*)((const float*)ginv + (size_t)s * TT);
                        #pragma unroll
                        for (int j = 0; j < 8; ++j) {
                            float4 v = p[j];
                            acc[j*4+0] += (v.x != 0.f) ? wv : 0.0;
                            acc[j*4+1] += (v.y != 0.f) ? wv : 0.0;
                            acc[j*4+2] += (v.z != 0.f) ? wv : 0.0;
                            acc[j*4+3] += (v.w != 0.f) ? wv : 0.0;
                        }
                    }
                } else {
                    const unsigned m = inMask[s];
                    #pragma unroll
                    for (int t = 0; t < TT; ++t)
                        acc[t] += ((m >> t) & 1u) ? wv : 0.0;
                }
            }
        }

        // CUBA scan.
        unsigned mask = 0;
        if (isbf) {
            // bf16 semantics: every add rounds to bf16; *0.5 and reset exact.
            float cur = 0.f, vol = 0.f;
            #pragma unroll
            for (int t = 0; t < TT; ++t) {
                const float z = f64_to_bf16_f32(acc[t]);      // conv output in bf16
                cur = round_bf16_f32(0.5f * cur + z);
                vol = round_bf16_f32(0.5f * vol + cur);
                const bool fire = (vol >= 1.0f);
                mask |= (fire ? 1u : 0u) << t;
                vol = fire ? 0.f : vol;
            }
        } else {
            double cur = 0.0, vol = 0.0;
            #pragma unroll
            for (int t = 0; t < TT; ++t) {
                cur = fma(0.5, cur, acc[t]);
                vol = fma(0.5, vol, cur);
                const bool fire = (vol >= 1.0);
                mask |= (fire ? 1u : 0u) << t;
                vol = fire ? 0.0 : vol;
            }
        }
        cnt = (float)__popc(mask);

        if (LAST) {
            if (isbf) {
                uint4* ob = (uint4*)((unsigned short*)goutv + (size_t)gid * TT);
                #pragma unroll
                for (int q = 0; q < 4; ++q) {
                    unsigned wd[4];
                    #pragma unroll
                    for (int m = 0; m < 4; ++m) {
                        const int t = (q * 4 + m) * 2;
                        wd[m] = (((mask >> t) & 1u) ? 0x3F80u : 0u)
                              | (((mask >> (t+1)) & 1u) ? 0x3F800000u : 0u);
                    }
                    ob[q] = make_uint4(wd[0], wd[1], wd[2], wd[3]);
                }
            } else {
                float4* ob = (float4*)((float*)goutv + (size_t)gid * TT);
                #pragma unroll
                for (int j = 0; j < 8; ++j) {
                    float4 s4;
                    s4.x = (mask >> (j*4+0)) & 1u ? 1.0f : 0.0f;
                    s4.y = (mask >> (j*4+1)) & 1u ? 1.0f : 0.0f;
                    s4.z = (mask >> (j*4+2)) & 1u ? 1.0f : 0.0f;
                    s4.w = (mask >> (j*4+3)) & 1u ? 1.0f : 0.0f;
                    ob[j] = s4;
                }
            }
        } else {
            outMask[gid] = mask;
        }
    }

    // Wave-level (64) count reduction; per-layer sums are integers < 2^24 so
    // fp32 atomic accumulation is exact.
    #pragma unroll
    for (int o = 32; o >= 1; o >>= 1) cnt += __shfl_down(cnt, o);
    if ((threadIdx.x & 63) == 0 && cnt > 0.f) atomicAdd(sumOut, cnt);
}

__global__ void finalize_counts(const float* __restrict__ sums,
                                void* __restrict__ out, const int* __restrict__ flag)
{
    int i = threadIdx.x;
    if (i < 3) {
        const float numel[3] = {7872512.f, 15239168.f, 3748096.f};
        float v = sums[i] / numel[i];
        if (flag[0]) ((unsigned short*)out)[3748096 + i] = f32_to_bf16_rne(v);
        else         ((float*)out)[3748096 + i] = v;
    }
}

extern "C" void kernel_launch(void* const* d_in, const int* in_sizes, int n_in,
                              void* d_out, int out_size, void* d_ws, size_t ws_size,
                              hipStream_t stream)
{
    const void* x  = d_in[0];  // [4,128,16,16,32] spikes (f32 or bf16)
    const void* w1 = d_in[1];  // [128,64,3,3]
    const void* w2 = d_in[2];  // [64,32,3,3]
    const void* w3 = d_in[3];  // [32,2,3,3]

    // Bit-packed intermediates: one u32 per site. Total ws < 3 MB.
    unsigned* buf1 = (unsigned*)d_ws;          // 4*64*31*31 = 246,016 words
    unsigned* buf2 = buf1 + 246016;            // 4*32*61*61 = 476,288 words
    float* sums = (float*)(buf2 + 476288);     // 3 floats
    int*   flag = (int*)(sums + 3);

    detect_and_init<<<1, 64, 0, stream>>>((const unsigned*)x, flag, sums);

    // L1: 128->64, 16x16 -> 31x31. total 246,016 = 961*256
    cuba_layer<128, 64, true,  false><<<961,  256, 0, stream>>>(
        x,    nullptr, w1, nullptr, buf1, 4, 16, 16, sums + 0, flag);
    // L2: 64->32, 31x31 -> 61x61. total 476,288 -> 1861 blocks
    cuba_layer<64,  32, false, false><<<1861, 256, 0, stream>>>(
        nullptr, buf1, w2, nullptr, buf2, 4, 31, 31, sums + 1, flag);
    // L3: 32->2, 61x61 -> 121x121. total 117,128 -> 458 blocks
    cuba_layer<32,  2,  false, true ><<<458,  256, 0, stream>>>(
        nullptr, buf2, w3, d_out,  nullptr, 4, 61, 61, sums + 2, flag);

    finalize_counts<<<1, 64, 0, stream>>>(sums, d_out, flag);
}